// Round 1
// baseline (116.773 us; speedup 1.0000x reference)
//
#include <hip/hip_runtime.h>

// Chamfer distance: B=8, N=M=8192, D=3, fp32, via bf16 split-precision MFMA.
// R8: R7 (45.4us partial) was stall-bound: busy pipes only ~17us VALU /
//     ~13us LDS / ~3.4us MFMA at 2 waves/SIMD (512 blocks, 16% occupancy).
//     (a) in-block m-split: waves 0,1 scan m-tiles 0..127 and waves 2,3
//         scan 128..255 for the SAME 4 n-tiles -> block covers 128 n ->
//         grid 16x64 = 1024 blocks = 4 blocks/CU = 4 waves/SIMD.
//         m-half mins combined via LDS (reuse sbuf) before lane reduce.
//     (b) j-pair min3: best = min3(best, d0[r], d1[r]) halves min-reduce
//         VALU (the largest pipe) and breaks the single-d-buffer WAR chain.
//     (c) global_load_lds width-16 staging (layout is wave-uniform base +
//         lane*16) -> no rg registers, no ds_write issue slots.

#define B_DIM 8
#define N_DIM 8192
#define MT    (N_DIM / 32)      // 256 m-tiles per (dir,b)
#define CH    8                 // tiles per chunk PER HALF (8 KB each)
#define NC    16                // chunks: each m-half = 128 tiles = 16*8
#define BLOCK 256
#define PPW   2                 // n-tiles per wave

typedef short  bf16x8 __attribute__((ext_vector_type(8)));
typedef float  f32x16 __attribute__((ext_vector_type(16)));

__device__ __forceinline__ unsigned short bf16_rne(float f) {
    unsigned int u = __float_as_uint(f);
    u += 0x7fffu + ((u >> 16) & 1u);
    return (unsigned short)(u >> 16);
}
__device__ __forceinline__ float bf16f(unsigned short h) {
    return __uint_as_float(((unsigned int)h) << 16);
}

// Pack B-fragments for both directions. Layout: 16-byte frags indexed
// [dirb][mtile][half][m32] so a wave's 64 lanes read 1024 contiguous bytes.
__global__ __launch_bounds__(256) void chamfer_prep(
    const float* __restrict__ pred, const float* __restrict__ gt,
    unsigned short* __restrict__ bpack, float* __restrict__ out)
{
    const int i   = blockIdx.x * 256 + threadIdx.x;  // 0 .. 2*B*N-1
    if (i == 0) out[0] = 0.0f;
    const int dir = i >> 16;
    const int bm  = i & 0xFFFF;                      // b*N + m
    const float* dst = dir ? pred : gt;
    const float x = dst[3*bm+0], y = dst[3*bm+1], z = dst[3*bm+2];
    const unsigned short hx = bf16_rne(x), hy = bf16_rne(y), hz = bf16_rne(z);
    const unsigned short lx = bf16_rne(x - bf16f(hx));
    const unsigned short ly = bf16_rne(y - bf16f(hy));
    const unsigned short lz = bf16_rne(z - bf16f(hz));
    const float gn = x*x + y*y + z*z;
    const unsigned short gnh = bf16_rne(gn), gnl = bf16_rne(gn - bf16f(gnh));
    const unsigned short one = 0x3F80;

    const int b  = bm >> 13, m = bm & (N_DIM - 1);
    const int mt = m >> 5,   c = m & 31;
    const int dirb = (dir << 3) | b;
    unsigned short* p0 = bpack + ((size_t)(dirb * MT + mt) * 64 + c) * 8;
    unsigned short* p1 = p0 + 32 * 8;
    // half0 = k0..7 : gh(xyz) gl(xyz) gh(x,y) ; half1 = k8..15 : gh(z) 1 1 gnh gnl 0 0 0
    bf16x8 h0 = {(short)hx,(short)hy,(short)hz,(short)lx,(short)ly,(short)lz,(short)hx,(short)hy};
    bf16x8 h1 = {(short)hz,(short)one,(short)one,(short)gnh,(short)gnl,0,0,0};
    *(bf16x8*)p0 = h0;
    *(bf16x8*)p1 = h1;
}

__global__ __launch_bounds__(BLOCK, 4) void chamfer_partial(
    const float* __restrict__ pred, const float* __restrict__ gt,
    const bf16x8* __restrict__ bpack, float* __restrict__ out)
{
    // [dbuf][half*512 + tile*64 + frag] : 2 x 16 KB
    __shared__ bf16x8 sbuf[2][1024];
    __shared__ float wsum[2];
    const int dirb = blockIdx.x;            // low grid bits -> spread over XCDs
    const int dir  = dirb >> 3, b = dirb & 7;
    const int w    = threadIdx.x >> 6, lane = threadIdx.x & 63;
    const int halfk = lane >> 5,  col = lane & 31;
    const int nsub = w & 1;                 // which n-tile pair
    const int mh   = w >> 1;                // which m-half (0: tiles 0..127, 1: 128..255)

    const float* src  = dir ? gt : pred;
    const float* srcb = src + (size_t)b * N_DIM * 3;

    // A fragments for this wave's PPW n-tiles (row = col, k-half = halfk).
    bf16x8 afrag[PPW];
    #pragma unroll
    for (int p = 0; p < PPW; ++p) {
        const int ntile = blockIdx.y * 4 + nsub * 2 + p;
        const int n = ntile * 32 + col;
        const float x = srcb[3*n+0], y = srcb[3*n+1], z = srcb[3*n+2];
        const float ax = -2.f*x, ay = -2.f*y, az = -2.f*z;
        const unsigned short ahx = bf16_rne(ax), ahy = bf16_rne(ay), ahz = bf16_rne(az);
        const unsigned short alx = bf16_rne(ax - bf16f(ahx));
        const unsigned short aly = bf16_rne(ay - bf16f(ahy));
        const unsigned short alz = bf16_rne(az - bf16f(ahz));
        const float pn = x*x + y*y + z*z;
        const unsigned short pnh = bf16_rne(pn), pnl = bf16_rne(pn - bf16f(pnh));
        const unsigned short one = 0x3F80;
        bf16x8 a0 = {(short)ahx,(short)ahy,(short)ahz,(short)ahx,(short)ahy,(short)ahz,(short)alx,(short)aly};
        bf16x8 a1 = {(short)alz,(short)pnh,(short)pnl,(short)one,(short)one,0,0,0};
        afrag[p] = (halfk == 0) ? a0 : a1;
    }

    const bf16x8* bp = bpack + (size_t)dirb * (MT * 64);

    // Stage one chunk (both halves, 16 KB) via global_load_lds.
    // Slot q = i*256 + tid; source frag = (i>>1)*8192 + c*512 + (q & 511).
    // LDS dest is wave-uniform base + lane*16 by construction.
#define STAGE(pb_, c_) { _Pragma("unroll") for (int i = 0; i < 4; ++i) { \
        const bf16x8* g_ = bp + ((i >> 1) * 8192 + (c_) * 512 + (i & 1) * 256 + w * 64 + lane); \
        __builtin_amdgcn_global_load_lds((__attribute__((address_space(1))) void*)g_, \
            (__attribute__((address_space(3))) void*)&sbuf[pb_][i * 256 + w * 64], 16, 0, 0); } }

    const f32x16 czero = {0.f,0.f,0.f,0.f,0.f,0.f,0.f,0.f,
                          0.f,0.f,0.f,0.f,0.f,0.f,0.f,0.f};
    float best[PPW][16];
    #pragma unroll
    for (int p = 0; p < PPW; ++p)
        #pragma unroll
        for (int r = 0; r < 16; ++r) best[p][r] = 1e30f;

    STAGE(0, 0);
    __syncthreads();

    for (int c = 0; c < NC; ++c) {
        const int pb = c & 1;
        if (c + 1 < NC) STAGE(pb ^ 1, c + 1);
        const bf16x8* sb = &sbuf[pb][mh * 512];
        #pragma unroll
        for (int j = 0; j < CH; j += 2) {
            const bf16x8 bc0 = sb[j * 64 + lane];
            const bf16x8 bc1 = sb[(j + 1) * 64 + lane];
            #pragma unroll
            for (int p = 0; p < PPW; ++p) {
                const f32x16 d0 = __builtin_amdgcn_mfma_f32_32x32x16_bf16(afrag[p], bc0, czero, 0, 0, 0);
                const f32x16 d1 = __builtin_amdgcn_mfma_f32_32x32x16_bf16(afrag[p], bc1, czero, 0, 0, 0);
                #pragma unroll
                for (int r = 0; r < 16; ++r)
                    best[p][r] = fminf(fminf(best[p][r], d0[r]), d1[r]);   // -> v_min3_f32
            }
        }
        __syncthreads();
    }

    // Combine the two m-halves: waves 2,3 export their best[] through LDS
    // (reuses sbuf[0]; last chunk read sbuf[1], barrier above protects it),
    // waves 0,1 min-combine. Layout keeps lanes contiguous -> conflict-free.
    float* cbuf = (float*)&sbuf[0][0];      // 4096 floats = 16 KB
    if (mh == 1) {
        #pragma unroll
        for (int p = 0; p < PPW; ++p)
            #pragma unroll
            for (int r = 0; r < 16; ++r)
                cbuf[(p * 16 + r) * 128 + nsub * 64 + lane] = best[p][r];
    }
    __syncthreads();
    if (mh == 0) {
        float bsum = 0.f;
        #pragma unroll
        for (int p = 0; p < PPW; ++p) {
            float s = 0.f;
            #pragma unroll
            for (int r = 0; r < 16; ++r) {
                float v = fminf(best[p][r], cbuf[(p * 16 + r) * 128 + nsub * 64 + lane]);
                v = fminf(v, __shfl_xor(v, 1,  64));
                v = fminf(v, __shfl_xor(v, 2,  64));
                v = fminf(v, __shfl_xor(v, 4,  64));
                v = fminf(v, __shfl_xor(v, 8,  64));
                v = fminf(v, __shfl_xor(v, 16, 64));
                s += v;                       // 16 final row-mins of this k-half
            }
            bsum += s + __shfl_xor(s, 32, 64);  // add other k-half's 16 rows
        }
        if (lane == 0) wsum[nsub] = bsum;
    }
    __syncthreads();
    if (threadIdx.x == 0) {
        const float scale = 100.0f * 0.5f / ((float)B_DIM * (float)N_DIM);
        atomicAdd(out, (wsum[0] + wsum[1]) * scale);
    }
}

extern "C" void kernel_launch(void* const* d_in, const int* in_sizes, int n_in,
                              void* d_out, int out_size, void* d_ws, size_t ws_size,
                              hipStream_t stream) {
    const float* pred = (const float*)d_in[0];
    const float* gt   = (const float*)d_in[1];
    float* out = (float*)d_out;
    unsigned short* bpack = (unsigned short*)d_ws;   // 4 MiB

    chamfer_prep<<<(2 * B_DIM * N_DIM) / 256, 256, 0, stream>>>(pred, gt, bpack, out);

    // dirb x n-chunks(128 pts) = 16 x 64 = 1024 blocks, 4/CU
    dim3 grid(16, N_DIM / 128);
    chamfer_partial<<<grid, BLOCK, 0, stream>>>(pred, gt, (const bf16x8*)bpack, out);
}

// Round 2
// 100.116 us; speedup vs baseline: 1.1664x; 1.1664x over previous
//
#include <hip/hip_runtime.h>

// Chamfer distance: B=8, N=M=8192, D=3, fp32, via bf16 split-precision MFMA.
// R9: R8 post-mortem: __launch_bounds__(256,4) made the allocator squeeze
//     to 64 VGPRs (8-waves/EU budget) while the min3 inner loop needs
//     best(32)+d0+d1(32)+afrag(8)+addr ~= 95 -> spilled f32x16 to scratch:
//     WRITE_SIZE 16KB -> 34.8MB, FETCH 2.9 -> 14.5MB, first dispatch 176us
//     (scratch first-touch), occupancy 34% not 50%.
//     Fix: __launch_bounds__(256,2) (VGPR cap 256, R7-proven). LDS (33KB)
//     already caps occupancy at the intended 4 blocks/CU; the hint was
//     pure downside. Everything else from R8 stays:
//     (a) in-block m-split: waves 0,1 scan m-tiles 0..127, waves 2,3 scan
//         128..255 for the SAME 4 n-tiles -> grid 16x64 = 1024 blocks.
//     (b) j-pair min3: best = min3(best, d0[r], d1[r]) halves min VALU.
//     (c) global_load_lds width-16 staging (no rg regs, no ds_writes).

#define B_DIM 8
#define N_DIM 8192
#define MT    (N_DIM / 32)      // 256 m-tiles per (dir,b)
#define CH    8                 // tiles per chunk PER HALF (8 KB each)
#define NC    16                // chunks: each m-half = 128 tiles = 16*8
#define BLOCK 256
#define PPW   2                 // n-tiles per wave

typedef short  bf16x8 __attribute__((ext_vector_type(8)));
typedef float  f32x16 __attribute__((ext_vector_type(16)));

__device__ __forceinline__ unsigned short bf16_rne(float f) {
    unsigned int u = __float_as_uint(f);
    u += 0x7fffu + ((u >> 16) & 1u);
    return (unsigned short)(u >> 16);
}
__device__ __forceinline__ float bf16f(unsigned short h) {
    return __uint_as_float(((unsigned int)h) << 16);
}

// Pack B-fragments for both directions. Layout: 16-byte frags indexed
// [dirb][mtile][half][m32] so a wave's 64 lanes read 1024 contiguous bytes.
__global__ __launch_bounds__(256) void chamfer_prep(
    const float* __restrict__ pred, const float* __restrict__ gt,
    unsigned short* __restrict__ bpack, float* __restrict__ out)
{
    const int i   = blockIdx.x * 256 + threadIdx.x;  // 0 .. 2*B*N-1
    if (i == 0) out[0] = 0.0f;
    const int dir = i >> 16;
    const int bm  = i & 0xFFFF;                      // b*N + m
    const float* dst = dir ? pred : gt;
    const float x = dst[3*bm+0], y = dst[3*bm+1], z = dst[3*bm+2];
    const unsigned short hx = bf16_rne(x), hy = bf16_rne(y), hz = bf16_rne(z);
    const unsigned short lx = bf16_rne(x - bf16f(hx));
    const unsigned short ly = bf16_rne(y - bf16f(hy));
    const unsigned short lz = bf16_rne(z - bf16f(hz));
    const float gn = x*x + y*y + z*z;
    const unsigned short gnh = bf16_rne(gn), gnl = bf16_rne(gn - bf16f(gnh));
    const unsigned short one = 0x3F80;

    const int b  = bm >> 13, m = bm & (N_DIM - 1);
    const int mt = m >> 5,   c = m & 31;
    const int dirb = (dir << 3) | b;
    unsigned short* p0 = bpack + ((size_t)(dirb * MT + mt) * 64 + c) * 8;
    unsigned short* p1 = p0 + 32 * 8;
    // half0 = k0..7 : gh(xyz) gl(xyz) gh(x,y) ; half1 = k8..15 : gh(z) 1 1 gnh gnl 0 0 0
    bf16x8 h0 = {(short)hx,(short)hy,(short)hz,(short)lx,(short)ly,(short)lz,(short)hx,(short)hy};
    bf16x8 h1 = {(short)hz,(short)one,(short)one,(short)gnh,(short)gnl,0,0,0};
    *(bf16x8*)p0 = h0;
    *(bf16x8*)p1 = h1;
}

__global__ __launch_bounds__(BLOCK, 2) void chamfer_partial(
    const float* __restrict__ pred, const float* __restrict__ gt,
    const bf16x8* __restrict__ bpack, float* __restrict__ out)
{
    // [dbuf][half*512 + tile*64 + frag] : 2 x 16 KB
    __shared__ bf16x8 sbuf[2][1024];
    __shared__ float wsum[2];
    const int dirb = blockIdx.x;            // low grid bits -> 2 streams/XCD in L2
    const int dir  = dirb >> 3, b = dirb & 7;
    const int w    = threadIdx.x >> 6, lane = threadIdx.x & 63;
    const int halfk = lane >> 5,  col = lane & 31;
    const int nsub = w & 1;                 // which n-tile pair
    const int mh   = w >> 1;                // which m-half (0: tiles 0..127, 1: 128..255)

    const float* src  = dir ? gt : pred;
    const float* srcb = src + (size_t)b * N_DIM * 3;

    // A fragments for this wave's PPW n-tiles (row = col, k-half = halfk).
    bf16x8 afrag[PPW];
    #pragma unroll
    for (int p = 0; p < PPW; ++p) {
        const int ntile = blockIdx.y * 4 + nsub * 2 + p;
        const int n = ntile * 32 + col;
        const float x = srcb[3*n+0], y = srcb[3*n+1], z = srcb[3*n+2];
        const float ax = -2.f*x, ay = -2.f*y, az = -2.f*z;
        const unsigned short ahx = bf16_rne(ax), ahy = bf16_rne(ay), ahz = bf16_rne(az);
        const unsigned short alx = bf16_rne(ax - bf16f(ahx));
        const unsigned short aly = bf16_rne(ay - bf16f(ahy));
        const unsigned short alz = bf16_rne(az - bf16f(ahz));
        const float pn = x*x + y*y + z*z;
        const unsigned short pnh = bf16_rne(pn), pnl = bf16_rne(pn - bf16f(pnh));
        const unsigned short one = 0x3F80;
        bf16x8 a0 = {(short)ahx,(short)ahy,(short)ahz,(short)ahx,(short)ahy,(short)ahz,(short)alx,(short)aly};
        bf16x8 a1 = {(short)alz,(short)pnh,(short)pnl,(short)one,(short)one,0,0,0};
        afrag[p] = (halfk == 0) ? a0 : a1;
    }

    const bf16x8* bp = bpack + (size_t)dirb * (MT * 64);

    // Stage one chunk (both halves, 16 KB) via global_load_lds.
    // Slot q = i*256 + tid; source frag = (i>>1)*8192 + c*512 + (q & 511).
    // LDS dest is wave-uniform base + lane*16 by construction.
#define STAGE(pb_, c_) { _Pragma("unroll") for (int i = 0; i < 4; ++i) { \
        const bf16x8* g_ = bp + ((i >> 1) * 8192 + (c_) * 512 + (i & 1) * 256 + w * 64 + lane); \
        __builtin_amdgcn_global_load_lds((__attribute__((address_space(1))) void*)g_, \
            (__attribute__((address_space(3))) void*)&sbuf[pb_][i * 256 + w * 64], 16, 0, 0); } }

    const f32x16 czero = {0.f,0.f,0.f,0.f,0.f,0.f,0.f,0.f,
                          0.f,0.f,0.f,0.f,0.f,0.f,0.f,0.f};
    float best[PPW][16];
    #pragma unroll
    for (int p = 0; p < PPW; ++p)
        #pragma unroll
        for (int r = 0; r < 16; ++r) best[p][r] = 1e30f;

    STAGE(0, 0);
    __syncthreads();

    for (int c = 0; c < NC; ++c) {
        const int pb = c & 1;
        if (c + 1 < NC) STAGE(pb ^ 1, c + 1);
        const bf16x8* sb = &sbuf[pb][mh * 512];
        #pragma unroll
        for (int j = 0; j < CH; j += 2) {
            const bf16x8 bc0 = sb[j * 64 + lane];
            const bf16x8 bc1 = sb[(j + 1) * 64 + lane];
            #pragma unroll
            for (int p = 0; p < PPW; ++p) {
                const f32x16 d0 = __builtin_amdgcn_mfma_f32_32x32x16_bf16(afrag[p], bc0, czero, 0, 0, 0);
                const f32x16 d1 = __builtin_amdgcn_mfma_f32_32x32x16_bf16(afrag[p], bc1, czero, 0, 0, 0);
                #pragma unroll
                for (int r = 0; r < 16; ++r)
                    best[p][r] = fminf(fminf(best[p][r], d0[r]), d1[r]);   // -> v_min3_f32
            }
        }
        __syncthreads();
    }

    // Combine the two m-halves: waves 2,3 export their best[] through LDS
    // (reuses sbuf[0]; last chunk read sbuf[1], barrier above protects it),
    // waves 0,1 min-combine. Layout keeps lanes contiguous -> conflict-free.
    float* cbuf = (float*)&sbuf[0][0];      // 4096 floats = 16 KB
    if (mh == 1) {
        #pragma unroll
        for (int p = 0; p < PPW; ++p)
            #pragma unroll
            for (int r = 0; r < 16; ++r)
                cbuf[(p * 16 + r) * 128 + nsub * 64 + lane] = best[p][r];
    }
    __syncthreads();
    if (mh == 0) {
        float bsum = 0.f;
        #pragma unroll
        for (int p = 0; p < PPW; ++p) {
            float s = 0.f;
            #pragma unroll
            for (int r = 0; r < 16; ++r) {
                float v = fminf(best[p][r], cbuf[(p * 16 + r) * 128 + nsub * 64 + lane]);
                v = fminf(v, __shfl_xor(v, 1,  64));
                v = fminf(v, __shfl_xor(v, 2,  64));
                v = fminf(v, __shfl_xor(v, 4,  64));
                v = fminf(v, __shfl_xor(v, 8,  64));
                v = fminf(v, __shfl_xor(v, 16, 64));
                s += v;                       // 16 final row-mins of this k-half
            }
            bsum += s + __shfl_xor(s, 32, 64);  // add other k-half's 16 rows
        }
        if (lane == 0) wsum[nsub] = bsum;
    }
    __syncthreads();
    if (threadIdx.x == 0) {
        const float scale = 100.0f * 0.5f / ((float)B_DIM * (float)N_DIM);
        atomicAdd(out, (wsum[0] + wsum[1]) * scale);
    }
}

extern "C" void kernel_launch(void* const* d_in, const int* in_sizes, int n_in,
                              void* d_out, int out_size, void* d_ws, size_t ws_size,
                              hipStream_t stream) {
    const float* pred = (const float*)d_in[0];
    const float* gt   = (const float*)d_in[1];
    float* out = (float*)d_out;
    unsigned short* bpack = (unsigned short*)d_ws;   // 4 MiB

    chamfer_prep<<<(2 * B_DIM * N_DIM) / 256, 256, 0, stream>>>(pred, gt, bpack, out);

    // dirb x n-chunks(128 pts) = 16 x 64 = 1024 blocks, LDS-capped 4/CU
    dim3 grid(16, N_DIM / 128);
    chamfer_partial<<<grid, BLOCK, 0, stream>>>(pred, gt, (const bf16x8*)bpack, out);
}